// Round 1
// baseline (1292.094 us; speedup 1.0000x reference)
//
#include <hip/hip_runtime.h>
#include <hip/hip_bf16.h>
#include <stdint.h>

using bf16x8 = __attribute__((ext_vector_type(8))) short;
using f32x4  = __attribute__((ext_vector_type(4))) float;

#define HP 58
#define WP 58

// ---------------------------------------------------------------------------
// Zero only the pad ring of ypad (228 border pixels per 58x58 frame, 256 ch).
// Interior is fully overwritten by temporal_stage. 466944 uint4 items total.
// ---------------------------------------------------------------------------
__global__ __launch_bounds__(256) void zero_ring(uint4* __restrict__ ypad) {
  uint4 z; z.x = z.y = z.z = z.w = 0u;
  int i = blockIdx.x * blockDim.x + threadIdx.x;   // grid sized exactly
  int v = i & 31;                                  // uint4 within pixel (32*16B=512B=256 bf16)
  int pr = i >> 5;
  int b = pr / 228;
  int r = pr - b * 228;
  int h, w;
  if (r < 58)       { h = 0;  w = r; }
  else if (r < 116) { h = 57; w = r - 58; }
  else { int rr = r - 116; h = 1 + (rr >> 1); w = (rr & 1) * 57; }
  ypad[(((long)b * HP + h) * WP + w) * 32 + v] = z;
}

// ---------------------------------------------------------------------------
// Per-channel dense tap table: wtab[c][j], j=0..6 <-> dt=j-3 (j=7 unused pad).
// ---------------------------------------------------------------------------
__global__ void wtab_prep(const float* __restrict__ w11, const float* __restrict__ w13,
                          const float* __restrict__ w15, const float* __restrict__ w17,
                          const float* __restrict__ w21, const float* __restrict__ w23,
                          const float* __restrict__ w25, const float* __restrict__ w27,
                          float* __restrict__ wtab) {
  int c = threadIdx.x;   // one block of 256
  float tv[8];
  #pragma unroll
  for (int j = 0; j < 8; ++j) tv[j] = 0.f;
  const float* wg; int K, cloc;
  if (c < 64) {
    int g = c >> 4; cloc = c & 15; K = 2 * g + 1;
    wg = (g == 0) ? w11 : (g == 1) ? w13 : (g == 2) ? w15 : w17;
  } else {
    int g = (c - 64) / 48; cloc = (c - 64) - g * 48; K = 2 * g + 1;
    wg = (g == 0) ? w21 : (g == 1) ? w23 : (g == 2) ? w25 : w27;
  }
  int P = (K - 1) >> 1;
  for (int k = 0; k < K; ++k) tv[3 + k - P] = wg[cloc * K + k];
  #pragma unroll
  for (int j = 0; j < 8; ++j) wtab[c * 8 + j] = tv[j];
}

// ---------------------------------------------------------------------------
// Weight prep: W[co][ci][kh][kw] f32  ->  Wb[kpos][co][ci] bf16
// ---------------------------------------------------------------------------
__global__ __launch_bounds__(256) void wprep(const float* __restrict__ w,
                                             unsigned short* __restrict__ out, int Cg) {
  int n = 9 * Cg * Cg;
  int stride = gridDim.x * blockDim.x;
  for (int i = blockIdx.x * blockDim.x + threadIdx.x; i < n; i += stride) {
    int kpos = i / (Cg * Cg);
    int r = i - kpos * Cg * Cg;
    int co = r / Cg;
    int ci = r - co * Cg;
    __hip_bfloat16 v = __float2bfloat16(w[(co * Cg + ci) * 9 + kpos]);
    out[(kpos * Cg + co) * Cg + ci] = *reinterpret_cast<unsigned short*>(&v);
  }
}

// ---------------------------------------------------------------------------
// Temporal depthwise conv + NCHW->padded-NHWC(bf16) layout change (unchanged).
// ---------------------------------------------------------------------------
__global__ __launch_bounds__(256) void temporal_stage(
    const float* __restrict__ x, const float* __restrict__ wtab,
    unsigned short* __restrict__ ypad)
{
  __shared__ float Ls[128][57];   // +1 pad -> conflict-free transpose
  int bid = blockIdx.x;
  int b = bid / 56;
  int h = bid - b * 56;
  int t = b & 7;                  // position within the 8-frame segment
  int tid = threadIdx.x;

  for (int half = 0; half < 2; ++half) {
    int cbase = half * 128;
    // phase 1: coalesced-over-w reads, dense temporal taps, stash f32 in LDS
    for (int idx = tid; idx < 128 * 56; idx += 256) {
      int cl = idx / 56;
      int w_ = idx - cl * 56;
      int c = cbase + cl;
      const float* wt = wtab + c * 8;
      const float* xp = x + ((long)b * 256 + c) * 3136 + h * 56 + w_;
      float acc = 0.f;
      #pragma unroll
      for (int j = 0; j < 7; ++j) {
        int tt = t + j - 3;                               // block-uniform
        int dtc = (tt < 0 ? 0 : (tt > 7 ? 7 : tt)) - t;   // clamped dt (uniform)
        float wj = wt[j];
        if (tt < 0 || tt > 7) wj = 0.f;                   // uniform select
        acc += wj * xp[(long)dtc * 802816];               // 256*3136 elems/frame
      }
      Ls[cl][w_] = acc;
    }
    __syncthreads();
    // phase 2: write channels-last (coalesced over c)
    for (int idx = tid; idx < 56 * 128; idx += 256) {
      int w_ = idx >> 7;
      int cl = idx & 127;
      __hip_bfloat16 v = __float2bfloat16(Ls[cl][w_]);
      ypad[(((long)b * HP + (h + 1)) * WP + (w_ + 1)) * 256 + cbase + cl] =
          *reinterpret_cast<unsigned short*>(&v);
    }
    __syncthreads();
  }
}

// ---------------------------------------------------------------------------
// Implicit-GEMM 3x3 conv, bf16 MFMA.  v2:
//   - block tile 256 px x 64 co (flat pixel tiles across frames; 784 exact)
//   - 4 waves stacked in M, per-wave 64x64 (4x4 acc) -> 4x fragment reuse
//   - reg-prefetch of next K-chunk's global loads overlapped with MFMA
//   - XCD-chunked bijective swizzle, ny-fastest so A-sharing blocks co-reside
// ---------------------------------------------------------------------------
template<int NKC>
__global__ __launch_bounds__(256) void conv_gemm2(
    const unsigned short* __restrict__ ypad,  // [64][58][58][256] bf16
    const unsigned short* __restrict__ wb,    // [9][Cg][Cg] bf16
    float* __restrict__ out,                  // [64][256][56][56] f32
    int co_base, int ci_base)
{
  constexpr int Cg  = NKC * 64;
  constexpr int NCH = 9 * NKC;                // K-chunks: kpos-major, kc-minor
  constexpr int NWG = 784 * NKC;

  __shared__ __align__(16) unsigned short As[256][72];  // +8 pad: ~2-way banks
  __shared__ __align__(16) unsigned short Bs[64][72];

  int tid = threadIdx.x;

  // XCD-chunked bijective remap (NWG % 8 == 0), ny fastest within a chunk so
  // the NKC blocks sharing one A-tile are consecutive on one XCD's L2.
  int gid = blockIdx.x;
  int wg  = (gid & 7) * (NWG >> 3) + (gid >> 3);
  int ny   = wg % NKC;
  int tile = wg / NKC;
  int p0   = tile * 256;                      // global pixel base (0..200448)

  // ---- staging assignment: thread stages A rows {sm, sm+64, +128, +192}
  //      and B row sm, 32B each at element offset klo.
  int sm  = tid >> 2;                         // 0..63
  int klo = (tid & 3) * 16;                   // element offset within BK=64

  const unsigned short* abase[4];
  #pragma unroll
  for (int m = 0; m < 4; ++m) {
    int gp = p0 + sm + 64 * m;
    int b  = gp / 3136;
    int p  = gp - b * 3136;
    int ph = p / 56;
    int pw = p - ph * 56;
    abase[m] = ypad + (((long)b * HP + ph) * WP + pw) * 256 + ci_base;
  }
  const unsigned short* bbase = wb + (long)(ny * 64 + sm) * Cg;

  uint4 ra[8], rb[2];
  auto issue = [&](int ch) {
    int kpos = ch / NKC;
    int kc   = ch - kpos * NKC;
    int kh   = kpos / 3;
    int kw   = kpos - kh * 3;
    int aoff = (kh * WP + kw) * 256 + kc * 64 + klo;
    #pragma unroll
    for (int m = 0; m < 4; ++m) {
      ra[2 * m]     = *reinterpret_cast<const uint4*>(abase[m] + aoff);
      ra[2 * m + 1] = *reinterpret_cast<const uint4*>(abase[m] + aoff + 8);
    }
    int boff = kpos * Cg * Cg + kc * 64 + klo;
    rb[0] = *reinterpret_cast<const uint4*>(bbase + boff);
    rb[1] = *reinterpret_cast<const uint4*>(bbase + boff + 8);
  };

  int wv   = tid >> 6;
  int lane = tid & 63;
  int l15  = lane & 15;
  int quad = lane >> 4;
  int qk   = quad * 8;
  int mi   = wv * 64;                         // wave's 64-pixel slab

  f32x4 acc[4][4];
  #pragma unroll
  for (int i = 0; i < 4; ++i)
    #pragma unroll
    for (int j = 0; j < 4; ++j) acc[i][j] = (f32x4){0.f, 0.f, 0.f, 0.f};

  issue(0);
  for (int ch = 0; ch < NCH; ++ch) {
    // drain staged regs to LDS (compiler inserts the vmcnt waits)
    *reinterpret_cast<uint4*>(&As[sm      ][klo])     = ra[0];
    *reinterpret_cast<uint4*>(&As[sm      ][klo + 8]) = ra[1];
    *reinterpret_cast<uint4*>(&As[sm +  64][klo])     = ra[2];
    *reinterpret_cast<uint4*>(&As[sm +  64][klo + 8]) = ra[3];
    *reinterpret_cast<uint4*>(&As[sm + 128][klo])     = ra[4];
    *reinterpret_cast<uint4*>(&As[sm + 128][klo + 8]) = ra[5];
    *reinterpret_cast<uint4*>(&As[sm + 192][klo])     = ra[6];
    *reinterpret_cast<uint4*>(&As[sm + 192][klo + 8]) = ra[7];
    *reinterpret_cast<uint4*>(&Bs[sm][klo])           = rb[0];
    *reinterpret_cast<uint4*>(&Bs[sm][klo + 8])       = rb[1];
    __syncthreads();

    // prefetch next chunk: latency hides under the 32 MFMAs below
    if (ch + 1 < NCH) issue(ch + 1);

    #pragma unroll
    for (int kk = 0; kk < 2; ++kk) {
      int ko = kk * 32 + qk;
      bf16x8 a0 = *reinterpret_cast<const bf16x8*>(&As[mi      + l15][ko]);
      bf16x8 a1 = *reinterpret_cast<const bf16x8*>(&As[mi + 16 + l15][ko]);
      bf16x8 a2 = *reinterpret_cast<const bf16x8*>(&As[mi + 32 + l15][ko]);
      bf16x8 a3 = *reinterpret_cast<const bf16x8*>(&As[mi + 48 + l15][ko]);
      bf16x8 b0 = *reinterpret_cast<const bf16x8*>(&Bs[     l15][ko]);
      bf16x8 b1 = *reinterpret_cast<const bf16x8*>(&Bs[16 + l15][ko]);
      bf16x8 b2 = *reinterpret_cast<const bf16x8*>(&Bs[32 + l15][ko]);
      bf16x8 b3 = *reinterpret_cast<const bf16x8*>(&Bs[48 + l15][ko]);
      acc[0][0] = __builtin_amdgcn_mfma_f32_16x16x32_bf16(a0, b0, acc[0][0], 0, 0, 0);
      acc[0][1] = __builtin_amdgcn_mfma_f32_16x16x32_bf16(a0, b1, acc[0][1], 0, 0, 0);
      acc[0][2] = __builtin_amdgcn_mfma_f32_16x16x32_bf16(a0, b2, acc[0][2], 0, 0, 0);
      acc[0][3] = __builtin_amdgcn_mfma_f32_16x16x32_bf16(a0, b3, acc[0][3], 0, 0, 0);
      acc[1][0] = __builtin_amdgcn_mfma_f32_16x16x32_bf16(a1, b0, acc[1][0], 0, 0, 0);
      acc[1][1] = __builtin_amdgcn_mfma_f32_16x16x32_bf16(a1, b1, acc[1][1], 0, 0, 0);
      acc[1][2] = __builtin_amdgcn_mfma_f32_16x16x32_bf16(a1, b2, acc[1][2], 0, 0, 0);
      acc[1][3] = __builtin_amdgcn_mfma_f32_16x16x32_bf16(a1, b3, acc[1][3], 0, 0, 0);
      acc[2][0] = __builtin_amdgcn_mfma_f32_16x16x32_bf16(a2, b0, acc[2][0], 0, 0, 0);
      acc[2][1] = __builtin_amdgcn_mfma_f32_16x16x32_bf16(a2, b1, acc[2][1], 0, 0, 0);
      acc[2][2] = __builtin_amdgcn_mfma_f32_16x16x32_bf16(a2, b2, acc[2][2], 0, 0, 0);
      acc[2][3] = __builtin_amdgcn_mfma_f32_16x16x32_bf16(a2, b3, acc[2][3], 0, 0, 0);
      acc[3][0] = __builtin_amdgcn_mfma_f32_16x16x32_bf16(a3, b0, acc[3][0], 0, 0, 0);
      acc[3][1] = __builtin_amdgcn_mfma_f32_16x16x32_bf16(a3, b1, acc[3][1], 0, 0, 0);
      acc[3][2] = __builtin_amdgcn_mfma_f32_16x16x32_bf16(a3, b2, acc[3][2], 0, 0, 0);
      acc[3][3] = __builtin_amdgcn_mfma_f32_16x16x32_bf16(a3, b3, acc[3][3], 0, 0, 0);
    }
    __syncthreads();
  }

  // epilogue: 4-row groups are frame-aligned (p0 % 4 == 0, 3136 % 4 == 0)
  #pragma unroll
  for (int i = 0; i < 4; ++i) {
    int gp0 = p0 + mi + i * 16 + quad * 4;
    int b   = gp0 / 3136;
    int p   = gp0 - b * 3136;
    #pragma unroll
    for (int j = 0; j < 4; ++j) {
      int co = co_base + ny * 64 + j * 16 + l15;
      float* ob = out + ((long)b * 256 + co) * 3136 + p;
      #pragma unroll
      for (int r = 0; r < 4; ++r) ob[r] = acc[i][j][r];
    }
  }
}

// ---------------------------------------------------------------------------
extern "C" void kernel_launch(void* const* d_in, const int* in_sizes, int n_in,
                              void* d_out, int out_size, void* d_ws, size_t ws_size,
                              hipStream_t stream) {
  const float* x    = (const float*)d_in[0];
  const float* w11  = (const float*)d_in[1];
  const float* w13  = (const float*)d_in[2];
  const float* w15  = (const float*)d_in[3];
  const float* w17  = (const float*)d_in[4];
  const float* w21  = (const float*)d_in[5];
  const float* w23  = (const float*)d_in[6];
  const float* w25  = (const float*)d_in[7];
  const float* w27  = (const float*)d_in[8];
  const float* w2d1 = (const float*)d_in[9];
  const float* w2d2 = (const float*)d_in[10];
  float* out = (float*)d_out;

  unsigned short* ypad = (unsigned short*)d_ws;
  size_t ypad_elems = (size_t)64 * HP * WP * 256;       // 110 MB bf16
  unsigned short* wb1 = ypad + ypad_elems;
  unsigned short* wb2 = wb1 + 9 * 64 * 64;

  // wtab lives in the first 8KB of d_out: consumed by temporal_stage, then
  // fully overwritten by conv_gemm2 (which writes every output element).
  float* wtab = out;

  hipLaunchKernelGGL(wtab_prep, dim3(1), dim3(256), 0, stream,
                     w11, w13, w15, w17, w21, w23, w25, w27, wtab);
  hipLaunchKernelGGL(zero_ring, dim3(1824), dim3(256), 0, stream, (uint4*)ypad);
  hipLaunchKernelGGL(wprep, dim3(32),  dim3(256), 0, stream, w2d1, wb1, 64);
  hipLaunchKernelGGL(wprep, dim3(256), dim3(256), 0, stream, w2d2, wb2, 192);
  hipLaunchKernelGGL(temporal_stage, dim3(64 * 56), dim3(256), 0, stream, x, wtab, ypad);
  hipLaunchKernelGGL((conv_gemm2<1>), dim3(784),     dim3(256), 0, stream, ypad, wb1, out, 0, 0);
  hipLaunchKernelGGL((conv_gemm2<3>), dim3(784 * 3), dim3(256), 0, stream, ypad, wb2, out, 64, 64);
}

// Round 3
// 708.820 us; speedup vs baseline: 1.8229x; 1.8229x over previous
//
#include <hip/hip_runtime.h>
#include <hip/hip_bf16.h>
#include <stdint.h>

using bf16x8 = __attribute__((ext_vector_type(8))) short;
using f32x4  = __attribute__((ext_vector_type(4))) float;

#define HP 58
#define WP 58

// ---------------------------------------------------------------------------
// async global -> LDS, 16B per lane (wave-uniform LDS base, per-lane source)
// ---------------------------------------------------------------------------
typedef __attribute__((address_space(1))) const unsigned int guint;
typedef __attribute__((address_space(3))) unsigned int       luint;
__device__ __forceinline__ void gload16(const unsigned short* g, unsigned short* l) {
  __builtin_amdgcn_global_load_lds((guint*)g, (luint*)l, 16, 0, 0);
}

// ---------------------------------------------------------------------------
// Zero only the pad ring of ypad (228 border pixels per 58x58 frame, 256 ch).
// ---------------------------------------------------------------------------
__global__ __launch_bounds__(256) void zero_ring(uint4* __restrict__ ypad) {
  uint4 z; z.x = z.y = z.z = z.w = 0u;
  int i = blockIdx.x * blockDim.x + threadIdx.x;   // grid sized exactly
  int v = i & 31;                                  // uint4 within pixel
  int pr = i >> 5;
  int b = pr / 228;
  int r = pr - b * 228;
  int h, w;
  if (r < 58)       { h = 0;  w = r; }
  else if (r < 116) { h = 57; w = r - 58; }
  else { int rr = r - 116; h = 1 + (rr >> 1); w = (rr & 1) * 57; }
  ypad[(((long)b * HP + h) * WP + w) * 32 + v] = z;
}

// ---------------------------------------------------------------------------
// Per-channel dense tap table: wtab[c][j], j=0..6 <-> dt=j-3 (j=7 unused pad).
// ---------------------------------------------------------------------------
__global__ void wtab_prep(const float* __restrict__ w11, const float* __restrict__ w13,
                          const float* __restrict__ w15, const float* __restrict__ w17,
                          const float* __restrict__ w21, const float* __restrict__ w23,
                          const float* __restrict__ w25, const float* __restrict__ w27,
                          float* __restrict__ wtab) {
  int c = threadIdx.x;   // one block of 256
  float tv[8];
  #pragma unroll
  for (int j = 0; j < 8; ++j) tv[j] = 0.f;
  const float* wg; int K, cloc;
  if (c < 64) {
    int g = c >> 4; cloc = c & 15; K = 2 * g + 1;
    wg = (g == 0) ? w11 : (g == 1) ? w13 : (g == 2) ? w15 : w17;
  } else {
    int g = (c - 64) / 48; cloc = (c - 64) - g * 48; K = 2 * g + 1;
    wg = (g == 0) ? w21 : (g == 1) ? w23 : (g == 2) ? w25 : w27;
  }
  int P = (K - 1) >> 1;
  for (int k = 0; k < K; ++k) tv[3 + k - P] = wg[cloc * K + k];
  #pragma unroll
  for (int j = 0; j < 8; ++j) wtab[c * 8 + j] = tv[j];
}

// ---------------------------------------------------------------------------
// Weight prep: W[co][ci][kh][kw] f32  ->  Wb[kpos][co][ci] bf16
// ---------------------------------------------------------------------------
__global__ __launch_bounds__(256) void wprep(const float* __restrict__ w,
                                             unsigned short* __restrict__ out, int Cg) {
  int n = 9 * Cg * Cg;
  int stride = gridDim.x * blockDim.x;
  for (int i = blockIdx.x * blockDim.x + threadIdx.x; i < n; i += stride) {
    int kpos = i / (Cg * Cg);
    int r = i - kpos * Cg * Cg;
    int co = r / Cg;
    int ci = r - co * Cg;
    __hip_bfloat16 v = __float2bfloat16(w[(co * Cg + ci) * 9 + kpos]);
    out[(kpos * Cg + co) * Cg + ci] = *reinterpret_cast<unsigned short*>(&v);
  }
}

// ---------------------------------------------------------------------------
// Temporal depthwise conv + NCHW->padded-NHWC(bf16) layout change (unchanged).
// ---------------------------------------------------------------------------
__global__ __launch_bounds__(256) void temporal_stage(
    const float* __restrict__ x, const float* __restrict__ wtab,
    unsigned short* __restrict__ ypad)
{
  __shared__ float Ls[128][57];   // +1 pad -> conflict-free transpose
  int bid = blockIdx.x;
  int b = bid / 56;
  int h = bid - b * 56;
  int t = b & 7;                  // position within the 8-frame segment
  int tid = threadIdx.x;

  for (int half = 0; half < 2; ++half) {
    int cbase = half * 128;
    for (int idx = tid; idx < 128 * 56; idx += 256) {
      int cl = idx / 56;
      int w_ = idx - cl * 56;
      int c = cbase + cl;
      const float* wt = wtab + c * 8;
      const float* xp = x + ((long)b * 256 + c) * 3136 + h * 56 + w_;
      float acc = 0.f;
      #pragma unroll
      for (int j = 0; j < 7; ++j) {
        int tt = t + j - 3;                               // block-uniform
        int dtc = (tt < 0 ? 0 : (tt > 7 ? 7 : tt)) - t;   // clamped dt (uniform)
        float wj = wt[j];
        if (tt < 0 || tt > 7) wj = 0.f;                   // uniform select
        acc += wj * xp[(long)dtc * 802816];               // 256*3136 elems/frame
      }
      Ls[cl][w_] = acc;
    }
    __syncthreads();
    for (int idx = tid; idx < 56 * 128; idx += 256) {
      int w_ = idx >> 7;
      int cl = idx & 127;
      __hip_bfloat16 v = __float2bfloat16(Ls[cl][w_]);
      ypad[(((long)b * HP + (h + 1)) * WP + (w_ + 1)) * 256 + cbase + cl] =
          *reinterpret_cast<unsigned short*>(&v);
    }
    __syncthreads();
  }
}

// ---------------------------------------------------------------------------
// Implicit-GEMM 3x3 conv, bf16 MFMA.  v3b (de-risked v3):
//   - 256px x 64co block tile, 4 waves in M, 64x64 per wave (4x4 acc)
//   - global_load_lds (16B) staging: zero staging VGPRs -> no spill
//   - double-buffered LDS (two STATIC buffer pairs), one __syncthreads per
//     chunk-half (2-phase schedule; barrier's vmcnt(0) drain lands after a
//     full 32-MFMA compute phase of latency cover)
//   - LINEAR LDS everywhere (swizzle dropped: T2 is timing-null at 2-phase,
//     m252; removes the riskiest machinery)
//   - XCD-chunked bijective blockIdx swizzle, ny-fastest (kept from v2;
//     proven: FETCH 962 -> 259 MB)
// ---------------------------------------------------------------------------
template<int NKC>
__global__ __launch_bounds__(256, 2) void conv_gemm3(
    const unsigned short* __restrict__ ypad,  // [64][58][58][256] bf16
    const unsigned short* __restrict__ wb,    // [9][Cg][Cg] bf16
    float* __restrict__ out,                  // [64][256][56][56] f32
    int co_base, int ci_base)
{
  constexpr int Cg  = NKC * 64;
  constexpr int NCH = 9 * NKC;                // K-chunks: kpos-major, kc-minor
  constexpr int NWG = 784 * NKC;

  __shared__ __align__(16) unsigned short As0[256][64];
  __shared__ __align__(16) unsigned short Bs0[64][64];
  __shared__ __align__(16) unsigned short As1[256][64];
  __shared__ __align__(16) unsigned short Bs1[64][64];

  int tid = threadIdx.x;

  // XCD-chunked bijective remap (NWG % 8 == 0), ny fastest within a chunk so
  // the NKC blocks sharing one A-tile are consecutive on one XCD's L2.
  int gid = blockIdx.x;
  int wg  = (gid & 7) * (NWG >> 3) + (gid >> 3);
  int ny   = wg % NKC;
  int tile = wg / NKC;
  int p0   = tile * 256;                      // global pixel base

  int l    = tid & 63;
  int w    = tid >> 6;
  int sub  = l >> 3;                          // 0..7: row within 8-row group
  int slot = l & 7;                           // 16B slot within a 128B row

  // A staging: wave w covers LDS rows [w*64, w*64+64), 8 issues of 8 rows.
  // gload16 dest = uniform row base + lane*16B -> lane l lands at
  // row (base + l>>3), elem (l&7)*8; source must match exactly (linear).
  const unsigned short* aptr[8];
  #pragma unroll
  for (int q = 0; q < 8; ++q) {
    int r  = w * 64 + q * 8 + sub;            // LDS row = pixel index in tile
    int gp = p0 + r;
    int b  = gp / 3136;
    int p  = gp - b * 3136;
    int ph = p / 56;
    int pw = p - ph * 56;
    aptr[q] = ypad + (((long)b * HP + ph) * WP + pw) * 256 + ci_base + slot * 8;
  }
  // B staging: wave w covers LDS rows [w*16, w*16+16), 2 issues of 8 rows.
  const unsigned short* bptr[2];
  #pragma unroll
  for (int q = 0; q < 2; ++q) {
    int r = w * 16 + q * 8 + sub;             // co within the 64-co tile
    bptr[q] = wb + (long)(ny * 64 + r) * Cg + slot * 8;
  }

  auto stage = [&](int ch, unsigned short (*A)[64], unsigned short (*B)[64]) {
    int kpos = ch / NKC;
    int kc   = ch - kpos * NKC;
    int kh   = kpos / 3;
    int kw   = kpos - kh * 3;
    long aoff = ((long)kh * WP + kw) * 256 + kc * 64;
    #pragma unroll
    for (int q = 0; q < 8; ++q)
      gload16(aptr[q] + aoff, &A[w * 64 + q * 8][0]);
    long boff = (long)kpos * Cg * Cg + kc * 64;
    #pragma unroll
    for (int q = 0; q < 2; ++q)
      gload16(bptr[q] + boff, &B[w * 16 + q * 8][0]);
  };

  int l15  = l & 15;
  int quad = l >> 4;
  int qk   = quad * 8;
  int mi   = w * 64;                          // wave's 64-pixel slab

  f32x4 acc[4][4];
  #pragma unroll
  for (int i = 0; i < 4; ++i)
    #pragma unroll
    for (int j = 0; j < 4; ++j) acc[i][j] = (f32x4){0.f, 0.f, 0.f, 0.f};

  auto compute = [&](const unsigned short (*A)[64], const unsigned short (*B)[64]) {
    #pragma unroll
    for (int kk = 0; kk < 2; ++kk) {
      int ko = kk * 32 + qk;
      bf16x8 a0 = *reinterpret_cast<const bf16x8*>(&A[mi      + l15][ko]);
      bf16x8 a1 = *reinterpret_cast<const bf16x8*>(&A[mi + 16 + l15][ko]);
      bf16x8 a2 = *reinterpret_cast<const bf16x8*>(&A[mi + 32 + l15][ko]);
      bf16x8 a3 = *reinterpret_cast<const bf16x8*>(&A[mi + 48 + l15][ko]);
      bf16x8 b0 = *reinterpret_cast<const bf16x8*>(&B[     l15][ko]);
      bf16x8 b1 = *reinterpret_cast<const bf16x8*>(&B[16 + l15][ko]);
      bf16x8 b2 = *reinterpret_cast<const bf16x8*>(&B[32 + l15][ko]);
      bf16x8 b3 = *reinterpret_cast<const bf16x8*>(&B[48 + l15][ko]);
      acc[0][0] = __builtin_amdgcn_mfma_f32_16x16x32_bf16(a0, b0, acc[0][0], 0, 0, 0);
      acc[0][1] = __builtin_amdgcn_mfma_f32_16x16x32_bf16(a0, b1, acc[0][1], 0, 0, 0);
      acc[0][2] = __builtin_amdgcn_mfma_f32_16x16x32_bf16(a0, b2, acc[0][2], 0, 0, 0);
      acc[0][3] = __builtin_amdgcn_mfma_f32_16x16x32_bf16(a0, b3, acc[0][3], 0, 0, 0);
      acc[1][0] = __builtin_amdgcn_mfma_f32_16x16x32_bf16(a1, b0, acc[1][0], 0, 0, 0);
      acc[1][1] = __builtin_amdgcn_mfma_f32_16x16x32_bf16(a1, b1, acc[1][1], 0, 0, 0);
      acc[1][2] = __builtin_amdgcn_mfma_f32_16x16x32_bf16(a1, b2, acc[1][2], 0, 0, 0);
      acc[1][3] = __builtin_amdgcn_mfma_f32_16x16x32_bf16(a1, b3, acc[1][3], 0, 0, 0);
      acc[2][0] = __builtin_amdgcn_mfma_f32_16x16x32_bf16(a2, b0, acc[2][0], 0, 0, 0);
      acc[2][1] = __builtin_amdgcn_mfma_f32_16x16x32_bf16(a2, b1, acc[2][1], 0, 0, 0);
      acc[2][2] = __builtin_amdgcn_mfma_f32_16x16x32_bf16(a2, b2, acc[2][2], 0, 0, 0);
      acc[2][3] = __builtin_amdgcn_mfma_f32_16x16x32_bf16(a2, b3, acc[2][3], 0, 0, 0);
      acc[3][0] = __builtin_amdgcn_mfma_f32_16x16x32_bf16(a3, b0, acc[3][0], 0, 0, 0);
      acc[3][1] = __builtin_amdgcn_mfma_f32_16x16x32_bf16(a3, b1, acc[3][1], 0, 0, 0);
      acc[3][2] = __builtin_amdgcn_mfma_f32_16x16x32_bf16(a3, b2, acc[3][2], 0, 0, 0);
      acc[3][3] = __builtin_amdgcn_mfma_f32_16x16x32_bf16(a3, b3, acc[3][3], 0, 0, 0);
    }
  };

  // 2-phase pipeline: stage(next) -> compute(cur) -> syncthreads (vmcnt drain)
  stage(0, As0, Bs0);
  __syncthreads();
  for (int ch = 0; ch < NCH; ch += 2) {
    if (ch + 1 < NCH) stage(ch + 1, As1, Bs1);
    compute(As0, Bs0);
    __syncthreads();
    if (ch + 1 < NCH) {
      if (ch + 2 < NCH) stage(ch + 2, As0, Bs0);
      compute(As1, Bs1);
      __syncthreads();
    }
  }

  // epilogue: 4-row groups are frame-aligned (p0 % 4 == 0, 3136 % 4 == 0)
  #pragma unroll
  for (int i = 0; i < 4; ++i) {
    int gp0 = p0 + mi + i * 16 + quad * 4;
    int b   = gp0 / 3136;
    int p   = gp0 - b * 3136;
    #pragma unroll
    for (int j = 0; j < 4; ++j) {
      int co = co_base + ny * 64 + j * 16 + l15;
      float* ob = out + ((long)b * 256 + co) * 3136 + p;
      #pragma unroll
      for (int r = 0; r < 4; ++r) ob[r] = acc[i][j][r];
    }
  }
}

// ---------------------------------------------------------------------------
extern "C" void kernel_launch(void* const* d_in, const int* in_sizes, int n_in,
                              void* d_out, int out_size, void* d_ws, size_t ws_size,
                              hipStream_t stream) {
  const float* x    = (const float*)d_in[0];
  const float* w11  = (const float*)d_in[1];
  const float* w13  = (const float*)d_in[2];
  const float* w15  = (const float*)d_in[3];
  const float* w17  = (const float*)d_in[4];
  const float* w21  = (const float*)d_in[5];
  const float* w23  = (const float*)d_in[6];
  const float* w25  = (const float*)d_in[7];
  const float* w27  = (const float*)d_in[8];
  const float* w2d1 = (const float*)d_in[9];
  const float* w2d2 = (const float*)d_in[10];
  float* out = (float*)d_out;

  unsigned short* ypad = (unsigned short*)d_ws;
  size_t ypad_elems = (size_t)64 * HP * WP * 256;       // 110 MB bf16
  unsigned short* wb1 = ypad + ypad_elems;
  unsigned short* wb2 = wb1 + 9 * 64 * 64;

  // wtab lives in the first 8KB of d_out: consumed by temporal_stage, then
  // fully overwritten by conv_gemm3 (which writes every output element).
  float* wtab = out;

  hipLaunchKernelGGL(wtab_prep, dim3(1), dim3(256), 0, stream,
                     w11, w13, w15, w17, w21, w23, w25, w27, wtab);
  hipLaunchKernelGGL(zero_ring, dim3(1824), dim3(256), 0, stream, (uint4*)ypad);
  hipLaunchKernelGGL(wprep, dim3(32),  dim3(256), 0, stream, w2d1, wb1, 64);
  hipLaunchKernelGGL(wprep, dim3(256), dim3(256), 0, stream, w2d2, wb2, 192);
  hipLaunchKernelGGL(temporal_stage, dim3(64 * 56), dim3(256), 0, stream, x, wtab, ypad);
  hipLaunchKernelGGL((conv_gemm3<1>), dim3(784),      dim3(256), 0, stream, ypad, wb1, out, 0, 0);
  hipLaunchKernelGGL((conv_gemm3<3>), dim3(784 * 3),  dim3(256), 0, stream, ypad, wb2, out, 64, 64);
}

// Round 4
// 631.805 us; speedup vs baseline: 2.0451x; 1.1219x over previous
//
#include <hip/hip_runtime.h>
#include <hip/hip_bf16.h>
#include <stdint.h>

using bf16x8 = __attribute__((ext_vector_type(8))) short;
using f32x4  = __attribute__((ext_vector_type(4))) float;

#define HP 58
#define WP 58

// ---------------------------------------------------------------------------
// async global -> LDS, 16B per lane (wave-uniform LDS base, per-lane source)
// ---------------------------------------------------------------------------
typedef __attribute__((address_space(1))) const unsigned int guint;
typedef __attribute__((address_space(3))) unsigned int       luint;
__device__ __forceinline__ void gload16(const unsigned short* g, unsigned short* l) {
  __builtin_amdgcn_global_load_lds((guint*)g, (luint*)l, 16, 0, 0);
}

// ---------------------------------------------------------------------------
// Zero only the pad ring of ypad (228 border pixels per 58x58 frame, 256 ch).
// ---------------------------------------------------------------------------
__global__ __launch_bounds__(256) void zero_ring(uint4* __restrict__ ypad) {
  uint4 z; z.x = z.y = z.z = z.w = 0u;
  int i = blockIdx.x * blockDim.x + threadIdx.x;   // grid sized exactly
  int v = i & 31;                                  // uint4 within pixel
  int pr = i >> 5;
  int b = pr / 228;
  int r = pr - b * 228;
  int h, w;
  if (r < 58)       { h = 0;  w = r; }
  else if (r < 116) { h = 57; w = r - 58; }
  else { int rr = r - 116; h = 1 + (rr >> 1); w = (rr & 1) * 57; }
  ypad[(((long)b * HP + h) * WP + w) * 32 + v] = z;
}

// ---------------------------------------------------------------------------
// Per-channel dense tap table: wtab[c][j], j=0..6 <-> dt=j-3 (j=7 unused pad).
// ---------------------------------------------------------------------------
__global__ void wtab_prep(const float* __restrict__ w11, const float* __restrict__ w13,
                          const float* __restrict__ w15, const float* __restrict__ w17,
                          const float* __restrict__ w21, const float* __restrict__ w23,
                          const float* __restrict__ w25, const float* __restrict__ w27,
                          float* __restrict__ wtab) {
  int c = threadIdx.x;   // one block of 256
  float tv[8];
  #pragma unroll
  for (int j = 0; j < 8; ++j) tv[j] = 0.f;
  const float* wg; int K, cloc;
  if (c < 64) {
    int g = c >> 4; cloc = c & 15; K = 2 * g + 1;
    wg = (g == 0) ? w11 : (g == 1) ? w13 : (g == 2) ? w15 : w17;
  } else {
    int g = (c - 64) / 48; cloc = (c - 64) - g * 48; K = 2 * g + 1;
    wg = (g == 0) ? w21 : (g == 1) ? w23 : (g == 2) ? w25 : w27;
  }
  int P = (K - 1) >> 1;
  for (int k = 0; k < K; ++k) tv[3 + k - P] = wg[cloc * K + k];
  #pragma unroll
  for (int j = 0; j < 8; ++j) wtab[c * 8 + j] = tv[j];
}

// ---------------------------------------------------------------------------
// Weight prep: W[co][ci][kh][kw] f32  ->  Wb[kpos][co][ci] bf16
// ---------------------------------------------------------------------------
__global__ __launch_bounds__(256) void wprep(const float* __restrict__ w,
                                             unsigned short* __restrict__ out, int Cg) {
  int n = 9 * Cg * Cg;
  int stride = gridDim.x * blockDim.x;
  for (int i = blockIdx.x * blockDim.x + threadIdx.x; i < n; i += stride) {
    int kpos = i / (Cg * Cg);
    int r = i - kpos * Cg * Cg;
    int co = r / Cg;
    int ci = r - co * Cg;
    __hip_bfloat16 v = __float2bfloat16(w[(co * Cg + ci) * 9 + kpos]);
    out[(kpos * Cg + co) * Cg + ci] = *reinterpret_cast<unsigned short*>(&v);
  }
}

// ---------------------------------------------------------------------------
// Temporal depthwise conv, v2: READ-ONCE.
// Block = (n, h, 32-channel slice). Stage all 8 frames x 32ch x 56w in LDS
// (float4 global loads -> ds_write_b64, [8][32][58] pad: 8B-aligned rows,
// 2-way banks = free). Each thread then computes all 8 temporal outputs for
// its channel from LDS (7 taps, f32) and writes channels-last bf16.
// x is read exactly once (205 MB) vs 7x re-reads from L2/L3 before.
// ---------------------------------------------------------------------------
__global__ __launch_bounds__(256, 2) void temporal_stage2(
    const float* __restrict__ x, const float* __restrict__ wtab,
    unsigned short* __restrict__ ypad)
{
  __shared__ float Ls[8][32][58];

  int bid = blockIdx.x;           // grid = 8n * 8ce * 56h = 3584
  int h   = bid % 56;
  int nce = bid / 56;
  int n   = nce >> 3;
  int ce  = nce & 7;
  int tid = threadIdx.x;

  // phase 1: load 8t x 32c x 14 float4 = 3584 items, 14 per thread
  for (int i = tid; i < 3584; i += 256) {
    int t = i / 448;              // 448 = 32c * 14f4
    int r = i - t * 448;
    int c = r / 14;
    int f = r - c * 14;
    const float4* src = reinterpret_cast<const float4*>(
        x + (((long)(n * 8 + t) * 256) + ce * 32 + c) * 3136 + h * 56 + f * 4);
    float4 v = *src;
    *reinterpret_cast<float2*>(&Ls[t][c][f * 4])     = make_float2(v.x, v.y);
    *reinterpret_cast<float2*>(&Ls[t][c][f * 4 + 2]) = make_float2(v.z, v.w);
  }
  __syncthreads();

  // phase 2: each thread owns channel c = tid&31; iterate (t,w) items
  int c  = tid & 31;
  int pi = tid >> 5;              // 0..7
  int cg = ce * 32 + c;
  float wt[7];
  #pragma unroll
  for (int j = 0; j < 7; ++j) wt[j] = wtab[cg * 8 + j];

  for (int k = pi; k < 448; k += 8) {   // 448 = 8t * 56w
    int t = k / 56;
    int w = k - t * 56;
    float acc = 0.f;
    #pragma unroll
    for (int j = 0; j < 7; ++j) {
      int tt  = t + j - 3;
      int ttc = tt < 0 ? 0 : (tt > 7 ? 7 : tt);
      float wj = (tt < 0 || tt > 7) ? 0.f : wt[j];
      acc += wj * Ls[ttc][c][w];
    }
    __hip_bfloat16 v = __float2bfloat16(acc);
    ypad[(((long)(n * 8 + t) * HP + (h + 1)) * WP + (w + 1)) * 256 + cg] =
        *reinterpret_cast<unsigned short*>(&v);
  }
}

// ---------------------------------------------------------------------------
// Implicit-GEMM 3x3 conv, bf16 MFMA.  v4 = v3b + XOR swizzle (rule #21):
//   - 256px x 64co block tile, 4 waves in M, 64x64 per wave (4x4 acc)
//   - global_load_lds (16B) staging: zero staging VGPRs
//   - double-buffered LDS, 2-phase schedule, one __syncthreads per half
//   - XOR involution: linear LDS dest, inverse-swizzled global SOURCE
//     (slot = (l&7)^(row&7)), swizzled ds_read (slot j -> j^(row&7)).
//     Kills the 16-way ds_read conflict of the linear 128B-stride layout.
//   - XCD-chunked bijective blockIdx swizzle, ny-fastest
// ---------------------------------------------------------------------------
template<int NKC>
__global__ __launch_bounds__(256, 2) void conv_gemm4(
    const unsigned short* __restrict__ ypad,  // [64][58][58][256] bf16
    const unsigned short* __restrict__ wb,    // [9][Cg][Cg] bf16
    float* __restrict__ out,                  // [64][256][56][56] f32
    int co_base, int ci_base)
{
  constexpr int Cg  = NKC * 64;
  constexpr int NCH = 9 * NKC;                // K-chunks: kpos-major, kc-minor
  constexpr int NWG = 784 * NKC;

  __shared__ __align__(16) unsigned short As0[256][64];
  __shared__ __align__(16) unsigned short Bs0[64][64];
  __shared__ __align__(16) unsigned short As1[256][64];
  __shared__ __align__(16) unsigned short Bs1[64][64];

  int tid = threadIdx.x;

  // XCD-chunked bijective remap (NWG % 8 == 0), ny fastest within a chunk.
  int gid = blockIdx.x;
  int wg  = (gid & 7) * (NWG >> 3) + (gid >> 3);
  int ny   = wg % NKC;
  int tile = wg / NKC;
  int p0   = tile * 256;                      // global pixel base

  int l   = tid & 63;
  int w   = tid >> 6;
  int sub = l >> 3;                           // row within 8-row group = row&7
  int swz = (l & 7) ^ sub;                    // inverse-swizzled source slot

  // A staging: wave w covers LDS rows [w*64, w*64+64), 8 issues of 8 rows.
  // gload16: lane l -> LDS row base+(l>>3), slot (l&7). Source slot swz
  // gives LDS[r][s] = G[r][s ^ (r&7)].
  const unsigned short* aptr[8];
  #pragma unroll
  for (int q = 0; q < 8; ++q) {
    int r  = w * 64 + q * 8 + sub;            // LDS row = pixel index in tile
    int gp = p0 + r;
    int b  = gp / 3136;
    int p  = gp - b * 3136;
    int ph = p / 56;
    int pw = p - ph * 56;
    aptr[q] = ypad + (((long)b * HP + ph) * WP + pw) * 256 + ci_base + swz * 8;
  }
  // B staging: wave w covers LDS rows [w*16, w*16+16), 2 issues of 8 rows.
  const unsigned short* bptr[2];
  #pragma unroll
  for (int q = 0; q < 2; ++q) {
    int r = w * 16 + q * 8 + sub;             // co within the 64-co tile
    bptr[q] = wb + (long)(ny * 64 + r) * Cg + swz * 8;
  }

  auto stage = [&](int ch, unsigned short (*A)[64], unsigned short (*B)[64]) {
    int kpos = ch / NKC;
    int kc   = ch - kpos * NKC;
    int kh   = kpos / 3;
    int kw   = kpos - kh * 3;
    long aoff = ((long)kh * WP + kw) * 256 + kc * 64;
    #pragma unroll
    for (int q = 0; q < 8; ++q)
      gload16(aptr[q] + aoff, &A[w * 64 + q * 8][0]);
    long boff = (long)kpos * Cg * Cg + kc * 64;
    #pragma unroll
    for (int q = 0; q < 2; ++q)
      gload16(bptr[q] + boff, &B[w * 16 + q * 8][0]);
  };

  int l15  = l & 15;
  int quad = l >> 4;
  int axor = l15 & 7;                         // row&7 of every frag row read
  int mi   = w * 64;                          // wave's 64-pixel slab

  f32x4 acc[4][4];
  #pragma unroll
  for (int i = 0; i < 4; ++i)
    #pragma unroll
    for (int j = 0; j < 4; ++j) acc[i][j] = (f32x4){0.f, 0.f, 0.f, 0.f};

  auto compute = [&](const unsigned short (*A)[64], const unsigned short (*B)[64]) {
    #pragma unroll
    for (int kk = 0; kk < 2; ++kk) {
      int soff = ((kk * 4 + quad) ^ axor) * 8;   // swizzled 16B slot
      bf16x8 a0 = *reinterpret_cast<const bf16x8*>(&A[mi      + l15][soff]);
      bf16x8 a1 = *reinterpret_cast<const bf16x8*>(&A[mi + 16 + l15][soff]);
      bf16x8 a2 = *reinterpret_cast<const bf16x8*>(&A[mi + 32 + l15][soff]);
      bf16x8 a3 = *reinterpret_cast<const bf16x8*>(&A[mi + 48 + l15][soff]);
      bf16x8 b0 = *reinterpret_cast<const bf16x8*>(&B[     l15][soff]);
      bf16x8 b1 = *reinterpret_cast<const bf16x8*>(&B[16 + l15][soff]);
      bf16x8 b2 = *reinterpret_cast<const bf16x8*>(&B[32 + l15][soff]);
      bf16x8 b3 = *reinterpret_cast<const bf16x8*>(&B[48 + l15][soff]);
      acc[0][0] = __builtin_amdgcn_mfma_f32_16x16x32_bf16(a0, b0, acc[0][0], 0, 0, 0);
      acc[0][1] = __builtin_amdgcn_mfma_f32_16x16x32_bf16(a0, b1, acc[0][1], 0, 0, 0);
      acc[0][2] = __builtin_amdgcn_mfma_f32_16x16x32_bf16(a0, b2, acc[0][2], 0, 0, 0);
      acc[0][3] = __builtin_amdgcn_mfma_f32_16x16x32_bf16(a0, b3, acc[0][3], 0, 0, 0);
      acc[1][0] = __builtin_amdgcn_mfma_f32_16x16x32_bf16(a1, b0, acc[1][0], 0, 0, 0);
      acc[1][1] = __builtin_amdgcn_mfma_f32_16x16x32_bf16(a1, b1, acc[1][1], 0, 0, 0);
      acc[1][2] = __builtin_amdgcn_mfma_f32_16x16x32_bf16(a1, b2, acc[1][2], 0, 0, 0);
      acc[1][3] = __builtin_amdgcn_mfma_f32_16x16x32_bf16(a1, b3, acc[1][3], 0, 0, 0);
      acc[2][0] = __builtin_amdgcn_mfma_f32_16x16x32_bf16(a2, b0, acc[2][0], 0, 0, 0);
      acc[2][1] = __builtin_amdgcn_mfma_f32_16x16x32_bf16(a2, b1, acc[2][1], 0, 0, 0);
      acc[2][2] = __builtin_amdgcn_mfma_f32_16x16x32_bf16(a2, b2, acc[2][2], 0, 0, 0);
      acc[2][3] = __builtin_amdgcn_mfma_f32_16x16x32_bf16(a2, b3, acc[2][3], 0, 0, 0);
      acc[3][0] = __builtin_amdgcn_mfma_f32_16x16x32_bf16(a3, b0, acc[3][0], 0, 0, 0);
      acc[3][1] = __builtin_amdgcn_mfma_f32_16x16x32_bf16(a3, b1, acc[3][1], 0, 0, 0);
      acc[3][2] = __builtin_amdgcn_mfma_f32_16x16x32_bf16(a3, b2, acc[3][2], 0, 0, 0);
      acc[3][3] = __builtin_amdgcn_mfma_f32_16x16x32_bf16(a3, b3, acc[3][3], 0, 0, 0);
    }
  };

  // 2-phase pipeline: stage(next) -> compute(cur) -> syncthreads (vmcnt drain)
  stage(0, As0, Bs0);
  __syncthreads();
  for (int ch = 0; ch < NCH; ch += 2) {
    if (ch + 1 < NCH) stage(ch + 1, As1, Bs1);
    compute(As0, Bs0);
    __syncthreads();
    if (ch + 1 < NCH) {
      if (ch + 2 < NCH) stage(ch + 2, As0, Bs0);
      compute(As1, Bs1);
      __syncthreads();
    }
  }

  // epilogue: 4-row groups are frame-aligned (p0 % 4 == 0, 3136 % 4 == 0)
  #pragma unroll
  for (int i = 0; i < 4; ++i) {
    int gp0 = p0 + mi + i * 16 + quad * 4;
    int b   = gp0 / 3136;
    int p   = gp0 - b * 3136;
    #pragma unroll
    for (int j = 0; j < 4; ++j) {
      int co = co_base + ny * 64 + j * 16 + l15;
      float* ob = out + ((long)b * 256 + co) * 3136 + p;
      #pragma unroll
      for (int r = 0; r < 4; ++r) ob[r] = acc[i][j][r];
    }
  }
}

// ---------------------------------------------------------------------------
extern "C" void kernel_launch(void* const* d_in, const int* in_sizes, int n_in,
                              void* d_out, int out_size, void* d_ws, size_t ws_size,
                              hipStream_t stream) {
  const float* x    = (const float*)d_in[0];
  const float* w11  = (const float*)d_in[1];
  const float* w13  = (const float*)d_in[2];
  const float* w15  = (const float*)d_in[3];
  const float* w17  = (const float*)d_in[4];
  const float* w21  = (const float*)d_in[5];
  const float* w23  = (const float*)d_in[6];
  const float* w25  = (const float*)d_in[7];
  const float* w27  = (const float*)d_in[8];
  const float* w2d1 = (const float*)d_in[9];
  const float* w2d2 = (const float*)d_in[10];
  float* out = (float*)d_out;

  unsigned short* ypad = (unsigned short*)d_ws;
  size_t ypad_elems = (size_t)64 * HP * WP * 256;       // 110 MB bf16
  unsigned short* wb1 = ypad + ypad_elems;
  unsigned short* wb2 = wb1 + 9 * 64 * 64;

  // wtab lives in the first 8KB of d_out: consumed by temporal_stage2, then
  // fully overwritten by conv_gemm4 (which writes every output element).
  float* wtab = out;

  hipLaunchKernelGGL(wtab_prep, dim3(1), dim3(256), 0, stream,
                     w11, w13, w15, w17, w21, w23, w25, w27, wtab);
  hipLaunchKernelGGL(zero_ring, dim3(1824), dim3(256), 0, stream, (uint4*)ypad);
  hipLaunchKernelGGL(wprep, dim3(32),  dim3(256), 0, stream, w2d1, wb1, 64);
  hipLaunchKernelGGL(wprep, dim3(256), dim3(256), 0, stream, w2d2, wb2, 192);
  hipLaunchKernelGGL(temporal_stage2, dim3(3584), dim3(256), 0, stream, x, wtab, ypad);
  hipLaunchKernelGGL((conv_gemm4<1>), dim3(784),     dim3(256), 0, stream, ypad, wb1, out, 0, 0);
  hipLaunchKernelGGL((conv_gemm4<3>), dim3(784 * 3), dim3(256), 0, stream, ypad, wb2, out, 64, 64);
}